// Round 3
// baseline (347.772 us; speedup 1.0000x reference)
//
#include <hip/hip_runtime.h>

// Sinkhorn as C = diag(u) * C0 * diag(v), node split across 4 waves for
// 8-waves/SIMD occupancy (the 1-wave/node version sat at 4 waves/SIMD and
// left the memory pipe idle during compute phases).
//
// Block = 256 threads = 4 waves = 1 node. Wave w owns rows 16w..16w+15.
// Lane L owns rows {16w + 4t + (L>>4)}, t=0..3 ; cols {4*(L&15)+k}, k=0..3
// (ownership induced by coalesced float4 loads at flat index 1024w+256t+4L).
//
// Per iteration:
//   col sums d_j = sum_i u_i C0[i,j] : lane-local FMA over t, fold xor16/32,
//     then 4-wave exchange of 64 partial col-sums via LDS (2 buffers,
//     1 barrier/iter) ; v_j = rcp(d_j)
//   row sums e_i = sum_j C0[i,j] v_j : lane-local FMA over k, fold xor1/2/4/8 ;
//     u_i = rcp(e_i)   (wave-local, no exchange needed)
// Final: out[i,j] = u_i * C0[i,j] * v_j.

#define LOG2E 1.4426950408889634f

__device__ __forceinline__ float fast_rcp(float x) {
    return __builtin_amdgcn_rcpf(x);
}
__device__ __forceinline__ float fast_exp2(float x) {
    return __builtin_amdgcn_exp2f(x);
}

__global__ __launch_bounds__(256, 8) void sinkhorn_kernel(
    const float* __restrict__ M, float* __restrict__ out, int num_node) {

    // [buffer][wave][column] partial column sums; 2 buffers alternate across
    // iterations so one barrier per iteration suffices (write buf, barrier,
    // read buf; next write to buf^1 can't race reads of buf that the
    // barrier already ordered).
    __shared__ float xch[2][4][64];

    const int node = blockIdx.x;
    if (node >= num_node) return;
    const int tid  = threadIdx.x;
    const int w    = tid >> 6;       // wave index: rows 16w..16w+15
    const int lane = tid & 63;
    const int cg   = lane & 15;      // column group: cols 4cg..4cg+3

    const float* __restrict__ Mn = M + (size_t)node * 4096 + 1024 * w;
    float* __restrict__ On = out + (size_t)node * 4096 + 1024 * w;

    // ---- load 16x64 slice, float4 per instruction, fully coalesced ----
    float c[4][4];
    #pragma unroll
    for (int t = 0; t < 4; ++t) {
        const float4 val = *reinterpret_cast<const float4*>(Mn + 256 * t + 4 * lane);
        c[t][0] = val.x; c[t][1] = val.y; c[t][2] = val.z; c[t][3] = val.w;
    }

    // ---- C0 = exp(sigmoid(clamp(M,-10,10)) / 0.01) via v_exp/v_rcp ----
    #pragma unroll
    for (int t = 0; t < 4; ++t) {
        #pragma unroll
        for (int k = 0; k < 4; ++k) {
            float x = c[t][k];
            x = fminf(10.0f, fmaxf(-10.0f, x));          // v_med3_f32
            float e = fast_exp2(-x * LOG2E);             // e^-x
            float s = fast_rcp(1.0f + e);                // sigmoid
            c[t][k] = fast_exp2(s * (100.0f * LOG2E));   // e^(s/gamma)
        }
    }

    float u[4] = {1.0f, 1.0f, 1.0f, 1.0f};
    float v[4] = {1.0f, 1.0f, 1.0f, 1.0f};

    #pragma unroll
    for (int it = 0; it < 5; ++it) {
        const int buf = it & 1;

        // ---- partial column sums for this wave's 16 rows ----
        float pd[4];
        #pragma unroll
        for (int k = 0; k < 4; ++k) {
            float a = 0.0f;
            #pragma unroll
            for (int t = 0; t < 4; ++t) a = fmaf(u[t], c[t][k], a);
            a += __shfl_xor(a, 16, 64);   // fold the 4 row-groups
            a += __shfl_xor(a, 32, 64);
            pd[k] = a;
        }
        // lanes 0..15 now hold the wave's partial sums for all 64 columns
        if (lane < 16) {
            *reinterpret_cast<float4*>(&xch[buf][w][4 * cg]) =
                make_float4(pd[0], pd[1], pd[2], pd[3]);
        }
        __syncthreads();

        // ---- combine the 4 wave-partials -> v ----
        {
            const float4 s0 = *reinterpret_cast<const float4*>(&xch[buf][0][4 * cg]);
            const float4 s1 = *reinterpret_cast<const float4*>(&xch[buf][1][4 * cg]);
            const float4 s2 = *reinterpret_cast<const float4*>(&xch[buf][2][4 * cg]);
            const float4 s3 = *reinterpret_cast<const float4*>(&xch[buf][3][4 * cg]);
            v[0] = fast_rcp(s0.x + s1.x + s2.x + s3.x);
            v[1] = fast_rcp(s0.y + s1.y + s2.y + s3.y);
            v[2] = fast_rcp(s0.z + s1.z + s2.z + s3.z);
            v[3] = fast_rcp(s0.w + s1.w + s2.w + s3.w);
        }

        // ---- row sums (wave-local) -> u ----
        #pragma unroll
        for (int t = 0; t < 4; ++t) {
            float a = 0.0f;
            #pragma unroll
            for (int k = 0; k < 4; ++k) a = fmaf(c[t][k], v[k], a);
            a += __shfl_xor(a, 1, 64);    // fold the 16 col-groups
            a += __shfl_xor(a, 2, 64);
            a += __shfl_xor(a, 4, 64);
            a += __shfl_xor(a, 8, 64);
            u[t] = fast_rcp(a);
        }
    }

    // ---- write out = u_i * C0[i,j] * v_j, coalesced float4 ----
    #pragma unroll
    for (int t = 0; t < 4; ++t) {
        float4 o;
        o.x = u[t] * c[t][0] * v[0];
        o.y = u[t] * c[t][1] * v[1];
        o.z = u[t] * c[t][2] * v[2];
        o.w = u[t] * c[t][3] * v[3];
        *reinterpret_cast<float4*>(On + 256 * t + 4 * lane) = o;
    }
}

extern "C" void kernel_launch(void* const* d_in, const int* in_sizes, int n_in,
                              void* d_out, int out_size, void* d_ws, size_t ws_size,
                              hipStream_t stream) {
    const float* M = (const float*)d_in[0];
    float* out = (float*)d_out;
    const int num_node = in_sizes[0] / 4096;   // 64*64 per node

    sinkhorn_kernel<<<num_node, 256, 0, stream>>>(M, out, num_node);
}

// Round 4
// 320.181 us; speedup vs baseline: 1.0862x; 1.0862x over previous
//
#include <hip/hip_runtime.h>

// Sinkhorn iteration factored as C = diag(u) * C0 * diag(v).
// One wave (64 lanes) per node, no barriers (R3 showed the 4-wave split's
// barriers align phases and regress). Lane L owns a 16x4 subtile:
//   rows {4t + (L>>4)}, t=0..15 ; cols {4*(L&15)+k}, k=0..3
// (ownership induced by coalesced float4 loads at flat index 256*t + 4*L).
//
// Row-group folds (within 16-lane DPP rows) use v_add_f32 row_ror DPP
// rotations instead of __shfl_xor: VALU-rate, no LDS pipe, ~25cy per
// 4-stage all-reduce vs ~140cy for 4 dependent ds_swizzles. Only the
// cross-row folds (xor 16/32, 8 per iteration) remain as shuffles.

#define LOG2E 1.4426950408889634f

__device__ __forceinline__ float fast_rcp(float x) {
    return __builtin_amdgcn_rcpf(x);
}
__device__ __forceinline__ float fast_exp2(float x) {
    return __builtin_amdgcn_exp2f(x);
}

// DPP row rotation within each 16-lane row (gfx9 DPP: row = 16 lanes).
// ctrl 0x120+N = row_ror:N. bound_ctrl=1, full row/bank masks.
template<int CTRL>
__device__ __forceinline__ float row_rot(float x) {
    return __int_as_float(__builtin_amdgcn_update_dpp(
        0, __float_as_int(x), CTRL, 0xF, 0xF, true));
}

// Sum all-reduce across each 16-lane row via rotations 8,4,2,1.
__device__ __forceinline__ float row16_allreduce_sum(float x) {
    x += row_rot<0x128>(x);   // + ror 8
    x += row_rot<0x124>(x);   // + ror 4
    x += row_rot<0x122>(x);   // + ror 2
    x += row_rot<0x121>(x);   // + ror 1
    return x;                 // every lane holds the row-of-16 sum
}

__global__ __launch_bounds__(256) void sinkhorn_kernel(
    const float* __restrict__ M, float* __restrict__ out, int num_node) {

    const int wavesPerBlock = blockDim.x >> 6;
    const int node = blockIdx.x * wavesPerBlock + (threadIdx.x >> 6);
    if (node >= num_node) return;
    const int lane = threadIdx.x & 63;

    const float* __restrict__ Mn = M + (size_t)node * 4096;
    float* __restrict__ On = out + (size_t)node * 4096;

    // ---- load 64x64 tile, float4 per instruction, fully coalesced ----
    float c[16][4];
    #pragma unroll
    for (int t = 0; t < 16; ++t) {
        const float4 val = *reinterpret_cast<const float4*>(Mn + 256 * t + 4 * lane);
        c[t][0] = val.x; c[t][1] = val.y; c[t][2] = val.z; c[t][3] = val.w;
    }

    // ---- C0 = exp(sigmoid(clamp(M,-10,10)) / 0.01) via v_exp/v_rcp ----
    #pragma unroll
    for (int t = 0; t < 16; ++t) {
        #pragma unroll
        for (int k = 0; k < 4; ++k) {
            float x = c[t][k];
            x = fminf(10.0f, fmaxf(-10.0f, x));          // v_med3_f32
            float e = fast_exp2(-x * LOG2E);             // e^-x
            float s = fast_rcp(1.0f + e);                // sigmoid
            c[t][k] = fast_exp2(s * (100.0f * LOG2E));   // e^(s/gamma)
        }
    }

    // ---- Sinkhorn scaling vectors ----
    float u[16];
    #pragma unroll
    for (int t = 0; t < 16; ++t) u[t] = 1.0f;
    float v[4] = {1.0f, 1.0f, 1.0f, 1.0f};

    #pragma unroll
    for (int it = 0; it < 5; ++it) {
        // column sums: d_j = sum_i u_i * C0[i,j]   (fold rows: lane-local
        // over t, then across the 4 row-groups = lanes differing in bits 4,5)
        float d[4];
        #pragma unroll
        for (int k = 0; k < 4; ++k) {
            float acc = 0.0f;
            #pragma unroll
            for (int t = 0; t < 16; ++t) acc = fmaf(u[t], c[t][k], acc);
            d[k] = acc;
        }
        #pragma unroll
        for (int k = 0; k < 4; ++k) {
            d[k] += __shfl_xor(d[k], 16, 64);
            d[k] += __shfl_xor(d[k], 32, 64);
            v[k] = fast_rcp(d[k]);
        }
        // row sums: e_i = sum_j C0[i,j] * v_j  (fold cols: lane-local over k,
        // then all-reduce across the 16-lane row via DPP rotations)
        #pragma unroll
        for (int t = 0; t < 16; ++t) {
            float acc = 0.0f;
            #pragma unroll
            for (int k = 0; k < 4; ++k) acc = fmaf(c[t][k], v[k], acc);
            u[t] = fast_rcp(row16_allreduce_sum(acc));
        }
    }

    // ---- write out = u_i * C0[i,j] * v_j, coalesced float4 ----
    #pragma unroll
    for (int t = 0; t < 16; ++t) {
        float4 o;
        o.x = u[t] * c[t][0] * v[0];
        o.y = u[t] * c[t][1] * v[1];
        o.z = u[t] * c[t][2] * v[2];
        o.w = u[t] * c[t][3] * v[3];
        *reinterpret_cast<float4*>(On + 256 * t + 4 * lane) = o;
    }
}

extern "C" void kernel_launch(void* const* d_in, const int* in_sizes, int n_in,
                              void* d_out, int out_size, void* d_ws, size_t ws_size,
                              hipStream_t stream) {
    const float* M = (const float*)d_in[0];
    float* out = (float*)d_out;
    const int num_node = in_sizes[0] / 4096;   // 64*64 per node

    const int wavesPerBlock = 4;               // 256 threads
    const int blocks = (num_node + wavesPerBlock - 1) / wavesPerBlock;
    sinkhorn_kernel<<<blocks, 256, 0, stream>>>(M, out, num_node);
}

// Round 6
// 292.723 us; speedup vs baseline: 1.1881x; 1.0938x over previous
//
#include <hip/hip_runtime.h>

// Sinkhorn iteration factored as C = diag(u) * C0 * diag(v).
// One wave (64 lanes) per node, no barriers (R3: multi-wave split + barriers
// regressed; occupancy is not the binding resource). Lane L owns a 16x4
// subtile: rows {4t + (L>>4)}, t=0..15 ; cols {4*(L&15)+k}, k=0..3
// (ownership induced by coalesced float4 loads at flat index 256*t + 4*L).
//
// R6 = R5 with the compile fix: __builtin_nontemporal_* needs a NATIVE
// vector type (clang ext_vector_type), not HIP_vector_type<float,4>.
// Every byte is touched exactly once, so `nt` tells L2/L3 not to retain.
// Row-group folds use v_add_f32 row_ror DPP (VALU pipe); cross-row folds
// (xor 16/32) remain shuffles (8 per iteration).

#define LOG2E 1.4426950408889634f

typedef float f32x4 __attribute__((ext_vector_type(4)));

__device__ __forceinline__ float fast_rcp(float x) {
    return __builtin_amdgcn_rcpf(x);
}
__device__ __forceinline__ float fast_exp2(float x) {
    return __builtin_amdgcn_exp2f(x);
}

// DPP row rotation within each 16-lane row (gfx9 DPP: row = 16 lanes).
// ctrl 0x120+N = row_ror:N. bound_ctrl=1, full row/bank masks.
template<int CTRL>
__device__ __forceinline__ float row_rot(float x) {
    return __int_as_float(__builtin_amdgcn_update_dpp(
        0, __float_as_int(x), CTRL, 0xF, 0xF, true));
}

// Sum all-reduce across each 16-lane row via rotations 8,4,2,1.
__device__ __forceinline__ float row16_allreduce_sum(float x) {
    x += row_rot<0x128>(x);   // + ror 8
    x += row_rot<0x124>(x);   // + ror 4
    x += row_rot<0x122>(x);   // + ror 2
    x += row_rot<0x121>(x);   // + ror 1
    return x;                 // every lane holds the row-of-16 sum
}

__global__ __launch_bounds__(256) void sinkhorn_kernel(
    const float* __restrict__ M, float* __restrict__ out, int num_node) {

    const int wavesPerBlock = blockDim.x >> 6;
    const int node = blockIdx.x * wavesPerBlock + (threadIdx.x >> 6);
    if (node >= num_node) return;
    const int lane = threadIdx.x & 63;

    const float* __restrict__ Mn = M + (size_t)node * 4096;
    float* __restrict__ On = out + (size_t)node * 4096;

    // ---- load 64x64 tile, non-temporal 16B loads, fully coalesced ----
    float c[16][4];
    #pragma unroll
    for (int t = 0; t < 16; ++t) {
        const f32x4 val = __builtin_nontemporal_load(
            reinterpret_cast<const f32x4*>(Mn + 256 * t + 4 * lane));
        c[t][0] = val.x; c[t][1] = val.y; c[t][2] = val.z; c[t][3] = val.w;
    }

    // ---- C0 = exp(sigmoid(clamp(M,-10,10)) / 0.01) via v_exp/v_rcp ----
    #pragma unroll
    for (int t = 0; t < 16; ++t) {
        #pragma unroll
        for (int k = 0; k < 4; ++k) {
            float x = c[t][k];
            x = fminf(10.0f, fmaxf(-10.0f, x));          // v_med3_f32
            float e = fast_exp2(-x * LOG2E);             // e^-x
            float s = fast_rcp(1.0f + e);                // sigmoid
            c[t][k] = fast_exp2(s * (100.0f * LOG2E));   // e^(s/gamma)
        }
    }

    // ---- Sinkhorn scaling vectors ----
    float u[16];
    #pragma unroll
    for (int t = 0; t < 16; ++t) u[t] = 1.0f;
    float v[4] = {1.0f, 1.0f, 1.0f, 1.0f};

    #pragma unroll
    for (int it = 0; it < 5; ++it) {
        // column sums: d_j = sum_i u_i * C0[i,j]   (fold rows: lane-local
        // over t, then across the 4 row-groups = lanes differing in bits 4,5)
        float d[4];
        #pragma unroll
        for (int k = 0; k < 4; ++k) {
            float acc = 0.0f;
            #pragma unroll
            for (int t = 0; t < 16; ++t) acc = fmaf(u[t], c[t][k], acc);
            d[k] = acc;
        }
        #pragma unroll
        for (int k = 0; k < 4; ++k) {
            d[k] += __shfl_xor(d[k], 16, 64);
            d[k] += __shfl_xor(d[k], 32, 64);
            v[k] = fast_rcp(d[k]);
        }
        // row sums: e_i = sum_j C0[i,j] * v_j  (fold cols: lane-local over k,
        // then all-reduce across the 16-lane row via DPP rotations)
        #pragma unroll
        for (int t = 0; t < 16; ++t) {
            float acc = 0.0f;
            #pragma unroll
            for (int k = 0; k < 4; ++k) acc = fmaf(c[t][k], v[k], acc);
            u[t] = fast_rcp(row16_allreduce_sum(acc));
        }
    }

    // ---- write out = u_i * C0[i,j] * v_j, non-temporal 16B stores ----
    #pragma unroll
    for (int t = 0; t < 16; ++t) {
        f32x4 o;
        o.x = u[t] * c[t][0] * v[0];
        o.y = u[t] * c[t][1] * v[1];
        o.z = u[t] * c[t][2] * v[2];
        o.w = u[t] * c[t][3] * v[3];
        __builtin_nontemporal_store(o, reinterpret_cast<f32x4*>(On + 256 * t + 4 * lane));
    }
}

extern "C" void kernel_launch(void* const* d_in, const int* in_sizes, int n_in,
                              void* d_out, int out_size, void* d_ws, size_t ws_size,
                              hipStream_t stream) {
    const float* M = (const float*)d_in[0];
    float* out = (float*)d_out;
    const int num_node = in_sizes[0] / 4096;   // 64*64 per node

    const int wavesPerBlock = 4;               // 256 threads
    const int blocks = (num_node + wavesPerBlock - 1) / wavesPerBlock;
    sinkhorn_kernel<<<blocks, 256, 0, stream>>>(M, out, num_node);
}